// Round 5
// baseline (795.151 us; speedup 1.0000x reference)
//
#include <hip/hip_runtime.h>
#include <hip/hip_bf16.h>
#include <cstdint>
#include <cstddef>

#define NVOX 300000
#define NVP  300032              /* padded plane stride (64-aligned) */
#define KNBR 27
#define COUT 32
#define W0E (KNBR * 16 * COUT)   /* 13824 */
#define WIE (KNBR * 32 * COUT)   /* 27648 */
#define WTOT (W0E + 4 * WIE)     /* 124416 */

typedef __hip_bfloat16 bf16;

__device__ __forceinline__ float bf2f(unsigned short u) {
    union { unsigned int i; float f; } x; x.i = ((unsigned int)u) << 16; return x.f;
}
__device__ __forceinline__ float load1f(const float* p) { return *p; }
__device__ __forceinline__ float load1f(const bf16* p) { return __bfloat162float(*p); }
__device__ __forceinline__ void store1(float* p, float v) { *p = v; }
__device__ __forceinline__ void store1(bf16* p, float v) { *p = __float2bfloat16(v); }
__device__ __forceinline__ unsigned short f2bfbits(float v) {
    bf16 h = __float2bfloat16(v);
    union { bf16 h; unsigned short u; } x; x.h = h; return x.u;
}

// ---- prep: detect dtype, transpose feat to SoA [c][v], copy weights to fp32
// natural [k][cin][cout], fold BN to (a,b), zero the correction counter ----
template<typename BufT>
__global__ __launch_bounds__(256)
void prep_kernel(const void* __restrict__ feat,
                 const void* w0, const void* w1, const void* w2, const void* w3, const void* w4,
                 const void* b0, const void* b1, const void* b2, const void* b3, const void* b4,
                 float* __restrict__ wt, float* __restrict__ bnab,
                 BufT* __restrict__ featc, int* __restrict__ flag, int* __restrict__ counter) {
    __shared__ int sflag;
    if (threadIdx.x == 0) {
        // bn_in gamma is uniform[0.5,1.5]: bf16 even ushorts decode into [0.25,4];
        // fp32 even ushorts are mantissa bits (random).
        const unsigned short* p = (const unsigned short*)b0;
        int hits = 0;
        for (int i = 0; i < 16; i++) {
            float v = bf2f(p[2 * i]);
            if (v >= 0.25f && v <= 4.0f) hits++;
        }
        sflag = (hits >= 8) ? 0 : 1;  // 0 = bf16 inputs, 1 = fp32 inputs
        if (blockIdx.x == 0) { *flag = sflag; *counter = 0; }
    }
    __syncthreads();
    const int fp32 = sflag;

    long long i = (long long)blockIdx.x * 256 + threadIdx.x;
    if (i < NVOX) {
        int v = (int)i;
        if (fp32) {
            const float* p = (const float*)feat + (size_t)v * 16;
#pragma unroll
            for (int j = 0; j < 16; j++) store1(featc + (size_t)j * NVP + v, p[j]);
        } else {
            const bf16* p = (const bf16*)feat + (size_t)v * 16;
#pragma unroll
            for (int j = 0; j < 16; j++) store1(featc + (size_t)j * NVP + v, __bfloat162float(p[j]));
        }
        return;
    }
    i -= NVOX;
    if (i < WTOT) {
        const void* w; long long rel;
        if (i < W0E) { w = w0; rel = i; }
        else {
            long long j = i - W0E; int L = (int)(j / WIE); rel = j % WIE;
            w = (L == 0) ? w1 : (L == 1) ? w2 : (L == 2) ? w3 : w4;
        }
        wt[i] = fp32 ? ((const float*)w)[rel] : __bfloat162float(((const bf16*)w)[rel]);
        return;
    }
    i -= WTOT;
    if (i < 160) {
        int L = (int)(i / 32), c = (int)(i % 32);
        const void* b = (L == 0) ? b0 : (L == 1) ? b1 : (L == 2) ? b2 : (L == 3) ? b3 : b4;
        float g, be, m, v;
        if (fp32) {
            const float* p = (const float*)b;
            g = p[c]; be = p[32 + c]; m = p[64 + c]; v = p[96 + c];
        } else {
            const bf16* p = (const bf16*)b;
            g = __bfloat162float(p[c]); be = __bfloat162float(p[32 + c]);
            m = __bfloat162float(p[64 + c]); v = __bfloat162float(p[96 + c]);
        }
        float a = g * rsqrtf(v + 1e-3f);
        bnab[L * 64 + c]      = a;
        bnab[L * 64 + 32 + c] = be - a * m;
    }
}

// ---- rulebook: append voxels having >=1 valid non-self neighbor to cvlist ----
__global__ __launch_bounds__(256)
void rulebook_kernel(const int* __restrict__ nbr,
                     int* __restrict__ cvlist, int* __restrict__ counter) {
    int t = blockIdx.x * 256 + threadIdx.x;
    int v = t >> 5;
    if (v >= NVOX) return;
    int k = t & 31;
    int lane = threadIdx.x & 63;
    int idx = (k < KNBR) ? nbr[(size_t)v * KNBR + k] : -1;
    bool valid = (idx >= 0) && (k != 13);
    unsigned long long full = __ballot(valid);
    unsigned int mask = (unsigned int)(full >> (lane & 32));
    if (k == 0 && mask) {
        int p = atomicAdd(counter, 1);
        cvlist[p] = v;
    }
}

// ---- dense self-term layer: 1 thread = 1 voxel, all 32 couts in VGPRs.
// x-loads fully coalesced (SoA planes); weights + BN wave-uniform (scalar).
// Branch-free; correction voxels are overwritten later by fix_kernel. ----
template<int CIN, typename BufT, bool HAS_RES, bool FINAL>
__global__ __launch_bounds__(256)
void dense_kernel(const BufT* __restrict__ in,     // SoA [CIN][NVP]
                  const float* __restrict__ w13,   // [CIN][32]
                  const float* __restrict__ bnab,  // a[32], b[32]
                  const BufT* __restrict__ res,    // SoA [32][NVP]
                  BufT* __restrict__ out,          // SoA [32][NVP]
                  void* __restrict__ out_base,
                  const int* __restrict__ flag) {
    int v = blockIdx.x * 256 + threadIdx.x;
    if (v >= NVOX) return;

    float acc[COUT];
#pragma unroll
    for (int c = 0; c < COUT; c++) acc[c] = 0.f;

#pragma unroll 4
    for (int j = 0; j < CIN; j++) {
        float x = load1f(in + (size_t)j * NVP + v);
        const float* wr = w13 + j * COUT;
#pragma unroll
        for (int c = 0; c < COUT; c++) acc[c] = fmaf(x, wr[c], acc[c]);
    }

#pragma unroll
    for (int c = 0; c < COUT; c++) {
        float y = fmaf(bnab[c], acc[c], bnab[32 + c]);
        if (HAS_RES) y += load1f(res + (size_t)c * NVP + v);
        acc[c] = fmaxf(y, 0.f);
    }

    if (FINAL) {
        float s = 0.f;
#pragma unroll
        for (int c = 0; c < COUT; c++) s += acc[c];  // acc >= 0
        float imp = 1.0f / (1.0f + expf(-s * (1.0f / 32.0f)));
        if (*flag) {
            float* ox = (float*)out_base;
#pragma unroll
            for (int c = 0; c < COUT; c += 4) {
                float4 t4{acc[c], acc[c + 1], acc[c + 2], acc[c + 3]};
                *(float4*)(ox + (size_t)v * COUT + c) = t4;
            }
            ox[(size_t)NVOX * COUT + v] = imp;
        } else {
            bf16* ox = (bf16*)out_base;
#pragma unroll
            for (int c = 0; c < COUT; c += 4) {
                ushort4 u{f2bfbits(acc[c]), f2bfbits(acc[c + 1]),
                          f2bfbits(acc[c + 2]), f2bfbits(acc[c + 3])};
                *(ushort4*)(ox + (size_t)v * COUT + c) = u;
            }
            ox[(size_t)NVOX * COUT + v] = __float2bfloat16(imp);
        }
    } else {
#pragma unroll
        for (int c = 0; c < COUT; c++) store1(out + (size_t)c * NVP + v, acc[c]);
    }
}

// ---- fix kernel: one wave per correction voxel (grid-stride over the compact
// list). Recomputes the FULL conv (self + neighbors via ballot on raw nbr) and
// overwrites dense_kernel's output for that voxel. ----
template<int CIN, typename BufT, bool HAS_RES, bool FINAL>
__global__ __launch_bounds__(256)
void fix_kernel(const BufT* __restrict__ in,       // SoA [CIN][NVP]
                const int* __restrict__ nbr,
                const int* __restrict__ cvlist, const int* __restrict__ count,
                const float* __restrict__ wt,      // [27][CIN][32]
                const float* __restrict__ bnab,
                const BufT* __restrict__ res,
                BufT* __restrict__ out,
                void* __restrict__ out_base,
                const int* __restrict__ flag) {
    int wid  = (blockIdx.x * 256 + threadIdx.x) >> 6;
    int nw   = (gridDim.x * 256) >> 6;
    int lane = threadIdx.x & 63;
    int c    = lane & 31;
    int n    = *count;

    for (int i = wid; i < n; i += nw) {
        int v = cvlist[i];
        float acc = 0.f;
        // self row
        {
            float xv = (lane < CIN) ? load1f(in + (size_t)lane * NVP + v) : 0.f;
            const float* wk = wt + (size_t)13 * CIN * COUT;
#pragma unroll 4
            for (int j = 0; j < CIN; j++) {
                float xj = __shfl(xv, j, 64);
                acc = fmaf(xj, wk[j * COUT + c], acc);
            }
        }
        // neighbor rows
        int idx = (lane < KNBR) ? nbr[(size_t)v * KNBR + lane] : -1;
        unsigned long long m = __ballot(idx >= 0) & 0x7FFFFFFULL;
        m &= ~(1ULL << 13);
        while (m) {
            int k = (int)__builtin_ctzll(m);
            m &= m - 1;
            int s = __shfl(idx, k, 64);
            float xv = (lane < CIN) ? load1f(in + (size_t)lane * NVP + s) : 0.f;
            const float* wk = wt + (size_t)k * CIN * COUT;
#pragma unroll 4
            for (int j = 0; j < CIN; j++) {
                float xj = __shfl(xv, j, 64);
                acc = fmaf(xj, wk[j * COUT + c], acc);
            }
        }

        float y = fmaf(bnab[c], acc, bnab[32 + c]);
        if (HAS_RES) y += load1f(res + (size_t)c * NVP + v);
        y = fmaxf(y, 0.f);

        if (FINAL) {
            float s2 = y;
#pragma unroll
            for (int o = 16; o > 0; o >>= 1) s2 += __shfl_xor(s2, o, 32);
            float imp = 1.0f / (1.0f + expf(-s2 * (1.0f / 32.0f)));
            if (*flag) {
                float* ox = (float*)out_base;
                if (lane < 32) ox[(size_t)v * COUT + c] = y;
                if (lane == 0) ox[(size_t)NVOX * COUT + v] = imp;
            } else {
                bf16* ox = (bf16*)out_base;
                if (lane < 32) ox[(size_t)v * COUT + c] = __float2bfloat16(y);
                if (lane == 0) ox[(size_t)NVOX * COUT + v] = __float2bfloat16(imp);
            }
        } else {
            if (lane < 32) store1(out + (size_t)c * NVP + v, y);
        }
    }
}

template<typename BufT>
static void run_pipeline(const void* const* d_in, void* d_out, char* ws, hipStream_t stream) {
    int*   flag    = (int*)ws;
    int*   counter = flag + 1;
    float* wt      = (float*)(ws + 1024);
    float* bnab    = wt + WTOT;
    int*   cvlist  = (int*)(ws + (1 << 20));
    char*  after   = (char*)(cvlist + NVOX);
    BufT*  featc = (BufT*)((((uintptr_t)after) + 255) & ~(uintptr_t)255);
    BufT*  X0 = featc + (size_t)16 * NVP;
    BufT*  X1 = X0 + (size_t)COUT * NVP;
    BufT*  X2 = X1 + (size_t)COUT * NVP;

    const void* feat = d_in[0];
    const int*  nbr  = (const int*)d_in[1];

    long long prep_total = (long long)NVOX + WTOT + 160;
    prep_kernel<BufT><<<dim3((unsigned)((prep_total + 255) / 256)), 256, 0, stream>>>(
        feat, d_in[2], d_in[4], d_in[6], d_in[8], d_in[10],
        d_in[3], d_in[5], d_in[7], d_in[9], d_in[11],
        wt, bnab, featc, flag, counter);

    rulebook_kernel<<<dim3((unsigned)(((size_t)NVOX * 32 + 255) / 256)), 256, 0, stream>>>(
        nbr, cvlist, counter);

    const float* wt0 = wt;
    const float* wt1 = wt0 + W0E;
    const float* wt2 = wt1 + WIE;
    const float* wt3 = wt2 + WIE;
    const float* wt4 = wt3 + WIE;
    const float* s0 = wt0 + 13 * 16 * COUT;
    const float* s1 = wt1 + 13 * 32 * COUT;
    const float* s2 = wt2 + 13 * 32 * COUT;
    const float* s3 = wt3 + 13 * 32 * COUT;
    const float* s4 = wt4 + 13 * 32 * COUT;

    dim3 gd((NVOX + 255) / 256);
    dim3 gf(512);

    // L0: feat -> X0
    dense_kernel<16, BufT, false, false><<<gd, 256, 0, stream>>>(featc, s0, bnab + 0 * 64, (const BufT*)nullptr, X0, nullptr, flag);
    fix_kernel<16, BufT, false, false><<<gf, 256, 0, stream>>>(featc, nbr, cvlist, counter, wt0, bnab + 0 * 64, (const BufT*)nullptr, X0, nullptr, flag);
    // L1: X0 -> X1
    dense_kernel<32, BufT, false, false><<<gd, 256, 0, stream>>>(X0, s1, bnab + 1 * 64, (const BufT*)nullptr, X1, nullptr, flag);
    fix_kernel<32, BufT, false, false><<<gf, 256, 0, stream>>>(X0, nbr, cvlist, counter, wt1, bnab + 1 * 64, (const BufT*)nullptr, X1, nullptr, flag);
    // L2: X1 (+res X0) -> X2
    dense_kernel<32, BufT, true, false><<<gd, 256, 0, stream>>>(X1, s2, bnab + 2 * 64, X0, X2, nullptr, flag);
    fix_kernel<32, BufT, true, false><<<gf, 256, 0, stream>>>(X1, nbr, cvlist, counter, wt2, bnab + 2 * 64, X0, X2, nullptr, flag);
    // L3: X2 -> X0
    dense_kernel<32, BufT, false, false><<<gd, 256, 0, stream>>>(X2, s3, bnab + 3 * 64, (const BufT*)nullptr, X0, nullptr, flag);
    fix_kernel<32, BufT, false, false><<<gf, 256, 0, stream>>>(X2, nbr, cvlist, counter, wt3, bnab + 3 * 64, (const BufT*)nullptr, X0, nullptr, flag);
    // L4: X0 (+res X2) -> d_out (AoS + imp)
    dense_kernel<32, BufT, true, true><<<gd, 256, 0, stream>>>(X0, s4, bnab + 4 * 64, X2, (BufT*)nullptr, d_out, flag);
    fix_kernel<32, BufT, true, true><<<gf, 256, 0, stream>>>(X0, nbr, cvlist, counter, wt4, bnab + 4 * 64, X2, (BufT*)nullptr, d_out, flag);
}

extern "C" void kernel_launch(void* const* d_in, const int* in_sizes, int n_in,
                              void* d_out, int out_size, void* d_ws, size_t ws_size,
                              hipStream_t stream) {
    char* ws = (char*)d_ws;
    size_t need_fp32 = (size_t)(1 << 20) + (size_t)NVOX * 4 + 512 +
                       (size_t)(16 + 3 * COUT) * NVP * sizeof(float);
    if (ws_size >= need_fp32) {
        run_pipeline<float>((const void* const*)d_in, d_out, ws, stream);
    } else {
        run_pipeline<bf16>((const void* const*)d_in, d_out, ws, stream);
    }
}

// Round 6
// 418.603 us; speedup vs baseline: 1.8995x; 1.8995x over previous
//
#include <hip/hip_runtime.h>
#include <hip/hip_bf16.h>
#include <cstdint>
#include <cstddef>

#define NVOX 300000
#define KNBR 27
#define COUT 32
#define W0E (KNBR * 16 * COUT)   /* 13824 */
#define WIE (KNBR * 32 * COUT)   /* 27648 */
#define WTOT (W0E + 4 * WIE)     /* 124416 */
#define FEATE (NVOX * 16)        /* 4800000 */

typedef __hip_bfloat16 bf16;

__device__ __forceinline__ float bf2f(unsigned short u) {
    union { unsigned int i; float f; } x; x.i = ((unsigned int)u) << 16; return x.f;
}
__device__ __forceinline__ unsigned short f2bfbits(float v) {
    bf16 h = __float2bfloat16(v);
    union { bf16 h; unsigned short u; } x; x.h = h; return x.u;
}
__device__ __forceinline__ float load1f(const float* p) { return *p; }
__device__ __forceinline__ float load1f(const bf16* p) { return __bfloat162float(*p); }
__device__ __forceinline__ float4 load4f(const float* p) { return *(const float4*)p; }
__device__ __forceinline__ float4 load4f(const bf16* p) {
    ushort4 u = *(const ushort4*)p;
    return float4{bf2f(u.x), bf2f(u.y), bf2f(u.z), bf2f(u.w)};
}
__device__ __forceinline__ void store1(float* p, float v) { *p = v; }
__device__ __forceinline__ void store1(bf16* p, float v) { *p = __float2bfloat16(v); }
__device__ __forceinline__ void store4(float* p, float a, float b, float c, float d) {
    *(float4*)p = float4{a, b, c, d};
}
__device__ __forceinline__ void store4(bf16* p, float a, float b, float c, float d) {
    *(ushort4*)p = ushort4{f2bfbits(a), f2bfbits(b), f2bfbits(c), f2bfbits(d)};
}

// ---- prep: detect dtype, canonicalize feat (AoS, coalesced copy) + weights to
// fp32 natural [k][cin][cout], fold BN to (a,b): y = a*acc + b ----
template<typename BufT>
__global__ __launch_bounds__(256)
void prep_kernel(const void* __restrict__ feat,
                 const void* w0, const void* w1, const void* w2, const void* w3, const void* w4,
                 const void* b0, const void* b1, const void* b2, const void* b3, const void* b4,
                 float* __restrict__ wt, float* __restrict__ bnab,
                 BufT* __restrict__ featc, int* __restrict__ flag, int* __restrict__ counter) {
    __shared__ int sflag;
    if (threadIdx.x == 0) {
        // bn_in gamma is uniform[0.5,1.5]: bf16 even ushorts decode into [0.25,4];
        // fp32 even ushorts are mantissa bits (random).
        const unsigned short* p = (const unsigned short*)b0;
        int hits = 0;
        for (int i = 0; i < 16; i++) {
            float v = bf2f(p[2 * i]);
            if (v >= 0.25f && v <= 4.0f) hits++;
        }
        sflag = (hits >= 8) ? 0 : 1;  // 0 = bf16 inputs, 1 = fp32 inputs
        if (blockIdx.x == 0) { *flag = sflag; *counter = 0; }
    }
    __syncthreads();
    const int fp32 = sflag;

    long long i = (long long)blockIdx.x * 256 + threadIdx.x;
    if (i < FEATE) {
        float v = fp32 ? ((const float*)feat)[i] : __bfloat162float(((const bf16*)feat)[i]);
        store1(featc + i, v);
        return;
    }
    i -= FEATE;
    if (i < WTOT) {
        const void* w; long long rel;
        if (i < W0E) { w = w0; rel = i; }
        else {
            long long j = i - W0E; int L = (int)(j / WIE); rel = j % WIE;
            w = (L == 0) ? w1 : (L == 1) ? w2 : (L == 2) ? w3 : w4;
        }
        wt[i] = fp32 ? ((const float*)w)[rel] : __bfloat162float(((const bf16*)w)[rel]);
        return;
    }
    i -= WTOT;
    if (i < 160) {
        int L = (int)(i / 32), c = (int)(i % 32);
        const void* b = (L == 0) ? b0 : (L == 1) ? b1 : (L == 2) ? b2 : (L == 3) ? b3 : b4;
        float g, be, m, v;
        if (fp32) {
            const float* p = (const float*)b;
            g = p[c]; be = p[32 + c]; m = p[64 + c]; v = p[96 + c];
        } else {
            const bf16* p = (const bf16*)b;
            g = __bfloat162float(p[c]); be = __bfloat162float(p[32 + c]);
            m = __bfloat162float(p[64 + c]); v = __bfloat162float(p[96 + c]);
        }
        float a = g * rsqrtf(v + 1e-3f);
        bnab[L * 64 + c]      = a;
        bnab[L * 64 + 32 + c] = be - a * m;
    }
}

// ---- rulebook: 256 voxels/block. Phase 1: coalesced 32-lane scans -> LDS
// flags. Phase 2: block-wide ballot compaction, ONE atomicAdd per block
// (1172 total vs 27k single-lane atomics that serialized R5 at 278us). ----
__global__ __launch_bounds__(256)
void rulebook_kernel(const int* __restrict__ nbr,
                     int* __restrict__ cvlist, int* __restrict__ counter) {
    __shared__ unsigned char flags[256];
    __shared__ int wsum[4];
    __shared__ int wbase[4];
    int tid  = threadIdx.x;
    int base = blockIdx.x * 256;
    int g    = tid >> 5;
    int k    = tid & 31;
    int lane = tid & 63;

    for (int it = 0; it < 32; it++) {
        int v = base + it * 8 + g;
        int idx = (v < NVOX && k < KNBR) ? nbr[(size_t)v * KNBR + k] : -1;
        bool valid = (idx >= 0) && (k != 13);
        unsigned long long full = __ballot(valid);
        unsigned int mask = (unsigned int)(full >> (lane & 32));
        if (k == 0) flags[it * 8 + g] = (mask != 0);
    }
    __syncthreads();

    bool f = flags[tid] != 0;
    unsigned long long wm = __ballot(f);
    int wid = tid >> 6;
    if (lane == 0) wsum[wid] = __popcll(wm);
    __syncthreads();
    if (tid == 0) {
        int t0 = wsum[0], t1 = wsum[1], t2 = wsum[2], t3 = wsum[3];
        int tot = t0 + t1 + t2 + t3;
        int b = tot ? atomicAdd(counter, tot) : 0;
        wbase[0] = b; wbase[1] = b + t0; wbase[2] = b + t0 + t1; wbase[3] = b + t0 + t1 + t2;
    }
    __syncthreads();
    if (f) {
        int pos = wbase[wid] + __popcll(wm & ((1ULL << lane) - 1ULL));
        cvlist[pos] = base + tid;
    }
}

// ---- dense self-term layer: 1 thread = 1 voxel, AoS rows. x loads are
// per-thread contiguous float4 (16B/lane), weights+BN wave-uniform scalar,
// stores float4. Branch-free; correction voxels overwritten by fix_kernel. ----
template<int CIN, typename BufT, bool HAS_RES, bool FINAL>
__global__ __launch_bounds__(256)
void dense_kernel(const BufT* __restrict__ in,     // AoS [NVOX][CIN]
                  const float* __restrict__ w13,   // [CIN][32]
                  const float* __restrict__ bnab,  // a[32], b[32]
                  const BufT* __restrict__ res,    // AoS [NVOX][32]
                  BufT* __restrict__ out,          // AoS [NVOX][32]
                  void* __restrict__ out_base,
                  const int* __restrict__ flag) {
    int v = blockIdx.x * 256 + threadIdx.x;
    if (v >= NVOX) return;

    float acc[COUT];
#pragma unroll
    for (int c = 0; c < COUT; c++) acc[c] = 0.f;

    const BufT* row = in + (size_t)v * CIN;
#pragma unroll
    for (int j = 0; j < CIN; j += 4) {
        float4 x = load4f(row + j);
        const float* wr = w13 + j * COUT;
#pragma unroll
        for (int c = 0; c < COUT; c++) {
            acc[c] = fmaf(x.x, wr[c], acc[c]);
            acc[c] = fmaf(x.y, wr[COUT + c], acc[c]);
            acc[c] = fmaf(x.z, wr[2 * COUT + c], acc[c]);
            acc[c] = fmaf(x.w, wr[3 * COUT + c], acc[c]);
        }
    }

#pragma unroll
    for (int c = 0; c < COUT; c++) acc[c] = fmaf(bnab[c], acc[c], bnab[32 + c]);
    if (HAS_RES) {
#pragma unroll
        for (int c = 0; c < COUT; c += 4) {
            float4 r = load4f(res + (size_t)v * COUT + c);
            acc[c] += r.x; acc[c + 1] += r.y; acc[c + 2] += r.z; acc[c + 3] += r.w;
        }
    }
#pragma unroll
    for (int c = 0; c < COUT; c++) acc[c] = fmaxf(acc[c], 0.f);

    if (FINAL) {
        float s = 0.f;
#pragma unroll
        for (int c = 0; c < COUT; c++) s += acc[c];  // acc >= 0
        float imp = 1.0f / (1.0f + expf(-s * (1.0f / 32.0f)));
        if (*flag) {
            float* ox = (float*)out_base;
#pragma unroll
            for (int c = 0; c < COUT; c += 4)
                store4(ox + (size_t)v * COUT + c, acc[c], acc[c + 1], acc[c + 2], acc[c + 3]);
            ox[(size_t)NVOX * COUT + v] = imp;
        } else {
            bf16* ox = (bf16*)out_base;
#pragma unroll
            for (int c = 0; c < COUT; c += 4)
                store4(ox + (size_t)v * COUT + c, acc[c], acc[c + 1], acc[c + 2], acc[c + 3]);
            ox[(size_t)NVOX * COUT + v] = __float2bfloat16(imp);
        }
    } else {
#pragma unroll
        for (int c = 0; c < COUT; c += 4)
            store4(out + (size_t)v * COUT + c, acc[c], acc[c + 1], acc[c + 2], acc[c + 3]);
    }
}

// ---- fix kernel: one wave per correction voxel (grid-stride over compact
// list). Recomputes the FULL conv (self included) and overwrites output. ----
template<int CIN, typename BufT, bool HAS_RES, bool FINAL>
__global__ __launch_bounds__(256)
void fix_kernel(const BufT* __restrict__ in,       // AoS [NVOX][CIN]
                const int* __restrict__ nbr,
                const int* __restrict__ cvlist, const int* __restrict__ count,
                const float* __restrict__ wt,      // [27][CIN][32]
                const float* __restrict__ bnab,
                const BufT* __restrict__ res,      // AoS [NVOX][32]
                BufT* __restrict__ out,
                void* __restrict__ out_base,
                const int* __restrict__ flag) {
    int wid  = (blockIdx.x * 256 + threadIdx.x) >> 6;
    int nw   = (gridDim.x * 256) >> 6;
    int lane = threadIdx.x & 63;
    int c    = lane & 31;
    int n    = *count;

    for (int i = wid; i < n; i += nw) {
        int v = cvlist[i];
        int idx = (lane < KNBR) ? nbr[(size_t)v * KNBR + lane] : -1;
        unsigned long long m = __ballot(idx >= 0) & ((1ULL << KNBR) - 1ULL);
        float acc = 0.f;
        while (m) {
            int k = (int)__builtin_ctzll(m);
            m &= m - 1;
            int src = __shfl(idx, k, 64);
            float xv = (lane < CIN) ? load1f(in + (size_t)src * CIN + lane) : 0.f;
            const float* wk = wt + (size_t)k * CIN * COUT + c;
#pragma unroll 8
            for (int j = 0; j < CIN; j++) {
                float xj = __shfl(xv, j, 64);
                acc = fmaf(xj, wk[j * COUT], acc);
            }
        }

        float y = fmaf(bnab[c], acc, bnab[32 + c]);
        if (HAS_RES) y += load1f(res + (size_t)v * COUT + c);
        y = fmaxf(y, 0.f);

        if (FINAL) {
            float s2 = y;
#pragma unroll
            for (int o = 16; o > 0; o >>= 1) s2 += __shfl_xor(s2, o, 32);
            float imp = 1.0f / (1.0f + expf(-s2 * (1.0f / 32.0f)));
            if (*flag) {
                float* ox = (float*)out_base;
                if (lane < 32) ox[(size_t)v * COUT + c] = y;
                if (lane == 0) ox[(size_t)NVOX * COUT + v] = imp;
            } else {
                bf16* ox = (bf16*)out_base;
                if (lane < 32) ox[(size_t)v * COUT + c] = __float2bfloat16(y);
                if (lane == 0) ox[(size_t)NVOX * COUT + v] = __float2bfloat16(imp);
            }
        } else {
            if (lane < 32) store1(out + (size_t)v * COUT + c, y);
        }
    }
}

template<typename BufT>
static void run_pipeline(const void* const* d_in, void* d_out, char* ws, hipStream_t stream) {
    int*   flag    = (int*)ws;
    int*   counter = flag + 1;
    float* wt      = (float*)(ws + 1024);
    float* bnab    = wt + WTOT;
    int*   cvlist  = (int*)(ws + (1 << 20));
    char*  after   = (char*)(cvlist + NVOX);
    BufT*  featc = (BufT*)((((uintptr_t)after) + 255) & ~(uintptr_t)255);
    BufT*  X0 = featc + FEATE;
    BufT*  X1 = X0 + (size_t)NVOX * COUT;
    BufT*  X2 = X1 + (size_t)NVOX * COUT;

    const void* feat = d_in[0];
    const int*  nbr  = (const int*)d_in[1];

    long long prep_total = (long long)FEATE + WTOT + 160;
    prep_kernel<BufT><<<dim3((unsigned)((prep_total + 255) / 256)), 256, 0, stream>>>(
        feat, d_in[2], d_in[4], d_in[6], d_in[8], d_in[10],
        d_in[3], d_in[5], d_in[7], d_in[9], d_in[11],
        wt, bnab, featc, flag, counter);

    rulebook_kernel<<<dim3((NVOX + 255) / 256), 256, 0, stream>>>(nbr, cvlist, counter);

    const float* wt0 = wt;
    const float* wt1 = wt0 + W0E;
    const float* wt2 = wt1 + WIE;
    const float* wt3 = wt2 + WIE;
    const float* wt4 = wt3 + WIE;
    const float* s0 = wt0 + 13 * 16 * COUT;
    const float* s1 = wt1 + 13 * 32 * COUT;
    const float* s2 = wt2 + 13 * 32 * COUT;
    const float* s3 = wt3 + 13 * 32 * COUT;
    const float* s4 = wt4 + 13 * 32 * COUT;

    dim3 gd((NVOX + 255) / 256);
    dim3 gf(1024);

    // L0: feat -> X0
    dense_kernel<16, BufT, false, false><<<gd, 256, 0, stream>>>(featc, s0, bnab + 0 * 64, (const BufT*)nullptr, X0, nullptr, flag);
    fix_kernel<16, BufT, false, false><<<gf, 256, 0, stream>>>(featc, nbr, cvlist, counter, wt0, bnab + 0 * 64, (const BufT*)nullptr, X0, nullptr, flag);
    // L1: X0 -> X1
    dense_kernel<32, BufT, false, false><<<gd, 256, 0, stream>>>(X0, s1, bnab + 1 * 64, (const BufT*)nullptr, X1, nullptr, flag);
    fix_kernel<32, BufT, false, false><<<gf, 256, 0, stream>>>(X0, nbr, cvlist, counter, wt1, bnab + 1 * 64, (const BufT*)nullptr, X1, nullptr, flag);
    // L2: X1 (+res X0) -> X2
    dense_kernel<32, BufT, true, false><<<gd, 256, 0, stream>>>(X1, s2, bnab + 2 * 64, X0, X2, nullptr, flag);
    fix_kernel<32, BufT, true, false><<<gf, 256, 0, stream>>>(X1, nbr, cvlist, counter, wt2, bnab + 2 * 64, X0, X2, nullptr, flag);
    // L3: X2 -> X0
    dense_kernel<32, BufT, false, false><<<gd, 256, 0, stream>>>(X2, s3, bnab + 3 * 64, (const BufT*)nullptr, X0, nullptr, flag);
    fix_kernel<32, BufT, false, false><<<gf, 256, 0, stream>>>(X2, nbr, cvlist, counter, wt3, bnab + 3 * 64, (const BufT*)nullptr, X0, nullptr, flag);
    // L4: X0 (+res X2) -> d_out (AoS + imp)
    dense_kernel<32, BufT, true, true><<<gd, 256, 0, stream>>>(X0, s4, bnab + 4 * 64, X2, (BufT*)nullptr, d_out, flag);
    fix_kernel<32, BufT, true, true><<<gf, 256, 0, stream>>>(X0, nbr, cvlist, counter, wt4, bnab + 4 * 64, X2, (BufT*)nullptr, d_out, flag);
}

extern "C" void kernel_launch(void* const* d_in, const int* in_sizes, int n_in,
                              void* d_out, int out_size, void* d_ws, size_t ws_size,
                              hipStream_t stream) {
    char* ws = (char*)d_ws;
    size_t need_fp32 = (size_t)(1 << 20) + (size_t)NVOX * 4 + 512 +
                       ((size_t)FEATE + 3ull * NVOX * COUT) * sizeof(float);
    if (ws_size >= need_fp32) {
        run_pipeline<float>((const void* const*)d_in, d_out, ws, stream);
    } else {
        run_pipeline<bf16>((const void* const*)d_in, d_out, ws, stream);
    }
}